// Round 3
// baseline (290.520 us; speedup 1.0000x reference)
//
#include <hip/hip_runtime.h>

typedef float  float4v __attribute__((ext_vector_type(4)));
typedef int    int4v   __attribute__((ext_vector_type(4)));

// Defensive scalar read: Python scalars arrive as 1-element arrays whose dtype
// may be int32 or float32.
__device__ __forceinline__ float scalar_as_float(const void* p) {
    int iv = *(const int*)p;
    if (iv >= -1000000 && iv <= 1000000) return (float)iv;
    return *(const float*)p;
}
__device__ __forceinline__ int scalar_as_int(const void* p) {
    int iv = *(const int*)p;
    if (iv >= -1000000 && iv <= 1000000) return iv;
    return (int)(*(const float*)p);
}

__device__ __forceinline__ float bce4(float4v xv, int4v iv, int mid, float t) {
    float s = 0.0f;
    #pragma unroll
    for (int j = 0; j < 4; ++j) {
        float xx = xv[j];
        float w  = (iv[j] >= mid) ? 2.0f : 1.0f;
        float a  = fabsf(xx);
        // stable BCE-with-logits: max(x,0) - x*t + log(1 + exp(-|x|))
        float bce = fmaxf(xx, 0.0f) - xx * t + __logf(1.0f + __expf(-a));
        s += w * bce;
    }
    return s;
}

__global__ __launch_bounds__(256) void rwl_partial_kernel(
        const float* __restrict__ x,
        const int*   __restrict__ idx,
        const void*  __restrict__ target_p,
        const void*  __restrict__ H_p,
        float* __restrict__ partials,
        int n_vec, int n_total)
{
    const float t   = scalar_as_float(target_p);
    const int   mid = scalar_as_int(H_p) >> 1;

    const int tid    = blockIdx.x * blockDim.x + threadIdx.x;
    const int stride = gridDim.x * blockDim.x;

    const float4v* __restrict__ xv4 = (const float4v*)x;
    const int4v*   __restrict__ iv4 = (const int4v*)idx;

    float acc0 = 0.0f, acc1 = 0.0f, acc2 = 0.0f, acc3 = 0.0f;

    // Batch 4 grid-stride iterations: 8 independent 16B loads in flight per
    // wave before any dependent compute (latency-bound fix, round 2).
    int i = tid;
    for (; i + 3 * stride < n_vec; i += 4 * stride) {
        float4v x0 = xv4[i];
        float4v x1 = xv4[i + stride];
        float4v x2 = xv4[i + 2 * stride];
        float4v x3 = xv4[i + 3 * stride];
        int4v   i0 = iv4[i];
        int4v   i1 = iv4[i + stride];
        int4v   i2 = iv4[i + 2 * stride];
        int4v   i3 = iv4[i + 3 * stride];
        acc0 += bce4(x0, i0, mid, t);
        acc1 += bce4(x1, i1, mid, t);
        acc2 += bce4(x2, i2, mid, t);
        acc3 += bce4(x3, i3, mid, t);
    }
    for (; i < n_vec; i += stride)
        acc0 += bce4(xv4[i], iv4[i], mid, t);

    float acc = (acc0 + acc1) + (acc2 + acc3);

    // scalar tail (N not divisible by 4) — global thread 0 only
    if (tid == 0) {
        for (int k = n_vec * 4; k < n_total; ++k) {
            float xx = x[k];
            float w  = (idx[k] >= mid) ? 2.0f : 1.0f;
            float a  = fabsf(xx);
            acc += w * (fmaxf(xx, 0.0f) - xx * t + __logf(1.0f + __expf(-a)));
        }
    }

    // wave-64 butterfly reduce
    #pragma unroll
    for (int off = 32; off > 0; off >>= 1)
        acc += __shfl_down(acc, off, 64);

    __shared__ float smem[4];
    const int lane = threadIdx.x & 63;
    const int wid  = threadIdx.x >> 6;
    if (lane == 0) smem[wid] = acc;
    __syncthreads();
    if (threadIdx.x == 0)
        partials[blockIdx.x] = smem[0] + smem[1] + smem[2] + smem[3];
}

__global__ __launch_bounds__(256) void rwl_final_kernel(
        const float* __restrict__ partials, int n, float inv_total,
        float* __restrict__ out)
{
    float acc = 0.0f;
    for (int i = threadIdx.x; i < n; i += 256) acc += partials[i];
    #pragma unroll
    for (int off = 32; off > 0; off >>= 1)
        acc += __shfl_down(acc, off, 64);
    __shared__ float smem[4];
    const int lane = threadIdx.x & 63;
    const int wid  = threadIdx.x >> 6;
    if (lane == 0) smem[wid] = acc;
    __syncthreads();
    if (threadIdx.x == 0)
        out[0] = (smem[0] + smem[1] + smem[2] + smem[3]) * inv_total;
}

extern "C" void kernel_launch(void* const* d_in, const int* in_sizes, int n_in,
                              void* d_out, int out_size, void* d_ws, size_t ws_size,
                              hipStream_t stream) {
    const float* x      = (const float*)d_in[0];
    const void*  target = d_in[1];
    const int*   idx    = (const int*)d_in[2];
    const void*  Hp     = d_in[3];
    float* out          = (float*)d_out;
    float* partials     = (float*)d_ws;

    const int n_total = in_sizes[0];
    const int n_vec   = n_total >> 2;

    // 8192 blocks: for N=2^25, each thread does exactly one 4-wide batch
    // (8 loads in flight), and 32 blocks/CU give wave-churn MLP.
    int blocks = (n_vec + 1023) / 1024;
    if (blocks > 8192) blocks = 8192;
    if (blocks < 1)    blocks = 1;

    rwl_partial_kernel<<<blocks, 256, 0, stream>>>(
        x, idx, target, Hp, partials, n_vec, n_total);

    const float inv_total = 1.0f / (float)n_total;
    rwl_final_kernel<<<1, 256, 0, stream>>>(partials, blocks, inv_total, out);
}

// Round 5
// 279.681 us; speedup vs baseline: 1.0388x; 1.0388x over previous
//
#include <hip/hip_runtime.h>

typedef float  float4v __attribute__((ext_vector_type(4)));
typedef int    int4v   __attribute__((ext_vector_type(4)));

// Defensive scalar read: Python scalars arrive as 1-element arrays whose dtype
// may be int32 or float32.
__device__ __forceinline__ float scalar_as_float(const void* p) {
    int iv = *(const int*)p;
    if (iv >= -1000000 && iv <= 1000000) return (float)iv;
    return *(const float*)p;
}
__device__ __forceinline__ int scalar_as_int(const void* p) {
    int iv = *(const int*)p;
    if (iv >= -1000000 && iv <= 1000000) return iv;
    return (int)(*(const float*)p);
}

// 4 independent element chains, pairwise-summed (short dependency tree).
__device__ __forceinline__ float bce4(float4v xv, int4v iv, int mid, float t) {
    float e[4];
    #pragma unroll
    for (int j = 0; j < 4; ++j) {
        float xx = xv[j];
        float w  = (iv[j] >= mid) ? 2.0f : 1.0f;
        float a  = fabsf(xx);
        // stable BCE-with-logits: max(x,0) - x*t + log(1 + exp(-|x|))
        float bce = fmaxf(xx, 0.0f) - xx * t + __logf(1.0f + __expf(-a));
        e[j] = w * bce;
    }
    return (e[0] + e[1]) + (e[2] + e[3]);
}

// launch_bounds(256, 4): allow up to 128 VGPR so the 2-deep x 2-wide software
// pipeline (4 x {float4,int4} live = ~56 data VGPRs + addresses) actually
// stays in registers. Round-3 lesson: default bounds squeezed to 36 VGPR and
// the compiler re-serialized the loads.
__global__ __launch_bounds__(256, 4) void rwl_partial_kernel(
        const float* __restrict__ x,
        const int*   __restrict__ idx,
        const void*  __restrict__ target_p,
        const void*  __restrict__ H_p,
        float* __restrict__ partials,
        int n_vec, int n_total, int uniform_iters)
{
    const float t   = scalar_as_float(target_p);
    const int   mid = scalar_as_int(H_p) >> 1;

    const int tid    = blockIdx.x * blockDim.x + threadIdx.x;
    const int stride = gridDim.x * blockDim.x;

    const float4v* __restrict__ xv4 = (const float4v*)x;
    const int4v*   __restrict__ iv4 = (const int4v*)idx;

    float acc = 0.0f, acc2 = 0.0f;

    if (uniform_iters >= 2) {
        // every thread runs exactly uniform_iters grid-stride iterations
        int i = tid;
        float4v xa = xv4[i];          int4v ia = iv4[i];
        float4v xb = xv4[i + stride]; int4v ib = iv4[i + stride];
        i += 2 * stride;
        int k = uniform_iters - 2;
        while (k >= 2) {
            // issue next 2 iterations' loads (4 x 16B in flight) ...
            float4v xc = xv4[i];          int4v ic  = iv4[i];
            float4v xd = xv4[i + stride]; int4v id_ = iv4[i + stride];
            // ... while computing on the current 2 (hides load latency)
            acc  += bce4(xa, ia, mid, t);
            acc2 += bce4(xb, ib, mid, t);
            xa = xc; ia = ic; xb = xd; ib = id_;
            i += 2 * stride; k -= 2;
        }
        if (k == 1) {
            float4v xc = xv4[i]; int4v ic = iv4[i];
            acc += bce4(xa, ia, mid, t);
            xa = xc; ia = ic;
        }
        acc  += bce4(xa, ia, mid, t);
        acc2 += bce4(xb, ib, mid, t);
    } else {
        for (int i = tid; i < n_vec; i += stride)
            acc += bce4(xv4[i], iv4[i], mid, t);
    }
    acc += acc2;

    // scalar tail (N not divisible by 4) — global thread 0 only
    if (tid == 0) {
        for (int kk = n_vec * 4; kk < n_total; ++kk) {
            float xx = x[kk];
            float w  = (idx[kk] >= mid) ? 2.0f : 1.0f;
            float a  = fabsf(xx);
            acc += w * (fmaxf(xx, 0.0f) - xx * t + __logf(1.0f + __expf(-a)));
        }
    }

    // wave-64 butterfly reduce
    #pragma unroll
    for (int off = 32; off > 0; off >>= 1)
        acc += __shfl_down(acc, off, 64);

    __shared__ float smem[4];
    const int lane = threadIdx.x & 63;
    const int wid  = threadIdx.x >> 6;
    if (lane == 0) smem[wid] = acc;
    __syncthreads();
    if (threadIdx.x == 0)
        partials[blockIdx.x] = smem[0] + smem[1] + smem[2] + smem[3];
}

__global__ __launch_bounds__(256) void rwl_final_kernel(
        const float* __restrict__ partials, int n, float inv_total,
        float* __restrict__ out)
{
    float acc = 0.0f;
    for (int i = threadIdx.x; i < n; i += 256) acc += partials[i];
    #pragma unroll
    for (int off = 32; off > 0; off >>= 1)
        acc += __shfl_down(acc, off, 64);
    __shared__ float smem[4];
    const int lane = threadIdx.x & 63;
    const int wid  = threadIdx.x >> 6;
    if (lane == 0) smem[wid] = acc;
    __syncthreads();
    if (threadIdx.x == 0)
        out[0] = (smem[0] + smem[1] + smem[2] + smem[3]) * inv_total;
}

extern "C" void kernel_launch(void* const* d_in, const int* in_sizes, int n_in,
                              void* d_out, int out_size, void* d_ws, size_t ws_size,
                              hipStream_t stream) {
    const float* x      = (const float*)d_in[0];
    const void*  target = d_in[1];
    const int*   idx    = (const int*)d_in[2];
    const void*  Hp     = d_in[3];
    float* out          = (float*)d_out;
    float* partials     = (float*)d_ws;

    const int n_total = in_sizes[0];
    const int n_vec   = n_total >> 2;

    int blocks = (n_vec + 1023) / 1024;
    if (blocks > 2048) blocks = 2048;
    if (blocks < 1)    blocks = 1;

    const int stride = blocks * 256;
    // uniform trip count only if every thread does the same number of iters
    const int uniform_iters = (n_vec % stride == 0) ? (n_vec / stride) : 0;

    rwl_partial_kernel<<<blocks, 256, 0, stream>>>(
        x, idx, target, Hp, partials, n_vec, n_total, uniform_iters);

    const float inv_total = 1.0f / (float)n_total;
    rwl_final_kernel<<<1, 256, 0, stream>>>(partials, blocks, inv_total, out);
}